// Round 1
// baseline (583.661 us; speedup 1.0000x reference)
//
#include <hip/hip_runtime.h>
#include <hip/hip_bf16.h>
#include <math.h>

#define BATCH 128
#define NEUR 54
#define DT 4
#define STEPS 30
#define PDIM 75            // pooled spatial dim
#define K (PDIM * PDIM)    // 5625
#define TOT (BATCH * NEUR) // 6912
#define RTPB 1024          // recurrence threads per block
#define PPT 7              // ceil(TOT / RTPB)

// ---------------- Kernel 1: avg_pool2d(x, 8) : [128,600,600] -> [128,75,75] --------
__global__ void pool_kernel(const float* __restrict__ x, float* __restrict__ xp) {
    int o = blockIdx.x * blockDim.x + threadIdx.x;
    if (o >= BATCH * K) return;
    int b = o / K;
    int rem = o - b * K;
    int i = rem / PDIM;
    int j = rem - i * PDIM;
    const float* base = x + (size_t)b * 360000 + (size_t)(i * 8) * 600 + j * 8;
    float s = 0.f;
#pragma unroll
    for (int r = 0; r < 8; r++) {
        const float4* p4 = (const float4*)(base + r * 600);
        float4 a = p4[0];
        float4 c = p4[1];
        s += a.x + a.y + a.z + a.w + c.x + c.y + c.z + c.w;
    }
    xp[o] = s * (1.0f / 64.0f);
}

// ---------------- Kernel 2: xf = xp @ fc_w.T + fc_b : [128,5625]x[54,5625] -> [128,54]
__global__ __launch_bounds__(256) void fc_kernel(const float* __restrict__ xp,
                                                 const float* __restrict__ fc_w,
                                                 const float* __restrict__ fc_b,
                                                 float* __restrict__ xf) {
    int b = blockIdx.x;
    int t = threadIdx.x;
    float acc[NEUR];
#pragma unroll
    for (int n = 0; n < NEUR; n++) acc[n] = 0.f;
    const float* xr = xp + (size_t)b * K;
    for (int k = t; k < K; k += 256) {
        float v = xr[k];
#pragma unroll
        for (int n = 0; n < NEUR; n++) acc[n] += v * fc_w[(size_t)n * K + k];
    }
    // reduce 256 threads -> 1 value per neuron. 4 waves of 64.
    __shared__ float sred[4][NEUR];
    int lane = t & 63, w = t >> 6;
#pragma unroll
    for (int n = 0; n < NEUR; n++) {
        float v = acc[n];
        for (int off = 32; off > 0; off >>= 1) v += __shfl_down(v, off, 64);
        if (lane == 0) sred[w][n] = v;
    }
    __syncthreads();
    if (t < NEUR) {
        float v = sred[0][t] + sred[1][t] + sred[2][t] + sred[3][t] + fc_b[t];
        xf[b * NEUR + t] = v;
    }
}

// ---------------- Kernel 3: 30-step GLM recurrence, single block --------------------
__global__ __launch_bounds__(RTPB) void recurrence_kernel(const float* __restrict__ xf,
                                                          const float* __restrict__ l_weight,
                                                          const float* __restrict__ h_weight,
                                                          float* __restrict__ out) {
    __shared__ float hs[TOT];      // per-(b,n) weighted history sums
    __shared__ float btot[BATCH];  // per-batch totals
    __shared__ float red[16];      // wave partials
    __shared__ float thr_s;

    int tid = threadIdx.x;
    float hw0 = h_weight[0], hw1 = h_weight[1], hw2 = h_weight[2], hw3 = h_weight[3];

    float hist[PPT][DT];
    float lw[PPT][DT];
    float xfv[PPT], cnt[PPT], rate[PPT];
    int bidx[PPT];

#pragma unroll
    for (int j = 0; j < PPT; j++) {
        int p = tid + j * RTPB;
        if (p < TOT) {
            int bb = p / NEUR;
            int n = p - bb * NEUR;
            bidx[j] = bb;
            xfv[j] = xf[p];
            cnt[j] = 0.f;
#pragma unroll
            for (int d = 0; d < DT; d++) {
                hist[j][d] = 0.f;
                lw[j][d] = l_weight[n * DT + d];
            }
        } else {
            bidx[j] = 0;
            xfv[j] = 0.f;
            cnt[j] = 0.f;
#pragma unroll
            for (int d = 0; d < DT; d++) { hist[j][d] = 0.f; lw[j][d] = 0.f; }
        }
    }

    for (int s = 0; s < STEPS; s++) {
        // 1) per-(b,n) l_weight-weighted history sum -> LDS
#pragma unroll
        for (int j = 0; j < PPT; j++) {
            int p = tid + j * RTPB;
            if (p < TOT) {
                hs[p] = hist[j][0] * lw[j][0] + hist[j][1] * lw[j][1] +
                        hist[j][2] * lw[j][2] + hist[j][3] * lw[j][3];
            }
        }
        __syncthreads();
        // 2) per-batch totals
        if (tid < BATCH) {
            float tsum = 0.f;
#pragma unroll
            for (int n = 0; n < NEUR; n++) tsum += hs[tid * NEUR + n];
            btot[tid] = tsum;
        }
        __syncthreads();
        // 3) current -> rate = exp(cur); local partial sum for global mean
        float lsum = 0.f;
#pragma unroll
        for (int j = 0; j < PPT; j++) {
            int p = tid + j * RTPB;
            if (p < TOT) {
                float hterm = hist[j][0] * hw0 + hist[j][1] * hw1 +
                              hist[j][2] * hw2 + hist[j][3] * hw3;
                float cur = xfv[j] + (btot[bidx[j]] - hs[p]) + hterm;
                rate[j] = expf(cur);
                lsum += rate[j];
            }
        }
        // 4) block-wide sum -> mean threshold
        float v = lsum;
        for (int off = 32; off > 0; off >>= 1) v += __shfl_down(v, off, 64);
        if ((tid & 63) == 0) red[tid >> 6] = v;
        __syncthreads();
        if (tid == 0) {
            float tsum = 0.f;
#pragma unroll
            for (int w = 0; w < 16; w++) tsum += red[w];
            thr_s = tsum * (1.0f / (float)TOT);
        }
        __syncthreads();
        float thr = thr_s;
        // 5) spike, count, shift history
#pragma unroll
        for (int j = 0; j < PPT; j++) {
            int p = tid + j * RTPB;
            if (p < TOT) {
                float sp = (rate[j] > thr) ? 1.0f : 0.0f;
                cnt[j] += sp;
                hist[j][0] = hist[j][1];
                hist[j][1] = hist[j][2];
                hist[j][2] = hist[j][3];
                hist[j][3] = sp;
            }
        }
        __syncthreads();
    }

    // softplus(count)
#pragma unroll
    for (int j = 0; j < PPT; j++) {
        int p = tid + j * RTPB;
        if (p < TOT) {
            float c = cnt[j];
            out[p] = c + log1pf(expf(-c));
        }
    }
}

extern "C" void kernel_launch(void* const* d_in, const int* in_sizes, int n_in,
                              void* d_out, int out_size, void* d_ws, size_t ws_size,
                              hipStream_t stream) {
    const float* x = (const float*)d_in[0];
    const float* l_weight = (const float*)d_in[1];
    const float* h_weight = (const float*)d_in[2];
    const float* fc_w = (const float*)d_in[3];
    const float* fc_b = (const float*)d_in[4];
    float* out = (float*)d_out;

    float* xp = (float*)d_ws;            // [128*5625] = 2.88 MB
    float* xf = xp + (size_t)BATCH * K;  // [6912]

    int pool_total = BATCH * K;
    pool_kernel<<<(pool_total + 255) / 256, 256, 0, stream>>>(x, xp);
    fc_kernel<<<BATCH, 256, 0, stream>>>(xp, fc_w, fc_b, xf);
    recurrence_kernel<<<1, RTPB, 0, stream>>>(xf, l_weight, h_weight, out);
}

// Round 2
// 381.844 us; speedup vs baseline: 1.5285x; 1.5285x over previous
//
#include <hip/hip_runtime.h>
#include <hip/hip_bf16.h>
#include <math.h>

#define BATCH 128
#define NEUR 54
#define DT 4
#define STEPS 30
#define PDIM 75             // pooled spatial dim
#define K (PDIM * PDIM)     // 5625
#define K_PAD 5632          // 5625 padded to multiple of 32 (8 kgroups x unroll4)
#define TOT (BATCH * NEUR)  // 6912
#define RTPB 1024           // recurrence threads per block

#define POOL_BLOCKS ((BATCH * K_PAD) / 256)       // 2816
#define TRANS_BLOCKS ((K_PAD * 64) / 256)         // 1408

// ---------------- Kernel 1 (fused): pool + weight transpose --------------------
// blocks [0, POOL_BLOCKS)          : avg_pool2d(x,8) -> xp [128][K_PAD] (pad zeroed)
// blocks [POOL_BLOCKS, +TRANS)     : fc_w [54,5625] -> fc_wt [K_PAD][64] (pad zeroed)
__global__ void prep_kernel(const float* __restrict__ x, const float* __restrict__ fc_w,
                            float* __restrict__ xp, float* __restrict__ fc_wt) {
    if (blockIdx.x < POOL_BLOCKS) {
        int o = blockIdx.x * 256 + threadIdx.x;          // over BATCH*K_PAD
        int b = o / K_PAD;
        int rem = o - b * K_PAD;
        if (rem >= K) { xp[o] = 0.f; return; }
        int i = rem / PDIM;
        int j = rem - i * PDIM;
        const float* base = x + (size_t)b * 360000 + (size_t)(i * 8) * 600 + j * 8;
        float s = 0.f;
#pragma unroll
        for (int r = 0; r < 8; r++) {
            const float4* p4 = (const float4*)(base + r * 600);
            float4 a = p4[0];
            float4 c = p4[1];
            s += a.x + a.y + a.z + a.w + c.x + c.y + c.z + c.w;
        }
        xp[o] = s * (1.0f / 64.0f);
    } else {
        int o = (blockIdx.x - POOL_BLOCKS) * 256 + threadIdx.x;  // over K_PAD*64
        int k = o >> 6;
        int n = o & 63;
        float v = (n < NEUR && k < K) ? fc_w[(size_t)n * K + k] : 0.f;
        fc_wt[o] = v;
    }
}

// ---------------- Kernel 2: xf = xp @ fc_wt + fc_b : [128,K]x[K,54] -> [128,54]
// One block per batch. lane n = neuron (54/64 active), kg = tid>>6 = k-slice.
// One accumulator chain per thread (x4 unroll) -> no spills.
__global__ __launch_bounds__(512) void fc_kernel(const float* __restrict__ xp,
                                                 const float* __restrict__ fc_wt,
                                                 const float* __restrict__ fc_b,
                                                 float* __restrict__ xf) {
    int b = blockIdx.x;
    int tid = threadIdx.x;
    int n = tid & 63;
    int kg = tid >> 6;  // 0..7
    const float* xr = xp + (size_t)b * K_PAD;
    float a0 = 0.f, a1 = 0.f, a2 = 0.f, a3 = 0.f;
    for (int k = kg; k < K_PAD; k += 32) {
        float x0 = xr[k];
        float x1 = xr[k + 8];
        float x2 = xr[k + 16];
        float x3 = xr[k + 24];
        a0 += x0 * fc_wt[(size_t)(k) * 64 + n];
        a1 += x1 * fc_wt[(size_t)(k + 8) * 64 + n];
        a2 += x2 * fc_wt[(size_t)(k + 16) * 64 + n];
        a3 += x3 * fc_wt[(size_t)(k + 24) * 64 + n];
    }
    float acc = (a0 + a1) + (a2 + a3);
    __shared__ float sred[8][64];
    sred[kg][n] = acc;
    __syncthreads();
    if (tid < 64) {
        float v = 0.f;
#pragma unroll
        for (int w = 0; w < 8; w++) v += sred[w][tid];
        if (tid < NEUR) xf[b * NEUR + tid] = v + fc_b[tid];
    }
}

// ---------------- Kernel 3: 30-step GLM recurrence, single block --------------------
// 8 threads per batch (8*128 = 1024). Each thread owns <=7 neurons.
// Per-batch lateral total: segmented shfl_xor over 8 lanes (no LDS).
// Global mean: wave shfl tree -> 16 partials -> double-buffered LDS, 1 barrier/step.
__global__ __launch_bounds__(RTPB) void recurrence_kernel(const float* __restrict__ xf,
                                                          const float* __restrict__ l_weight,
                                                          const float* __restrict__ h_weight,
                                                          float* __restrict__ out) {
    __shared__ float red[2][16];

    int tid = threadIdx.x;
    int b = tid >> 3;
    int sub = tid & 7;
    int n0 = sub * 7;                       // neurons n0 .. n0+cntn-1
    int cntn = NEUR - n0; if (cntn > 7) cntn = 7; if (cntn < 0) cntn = 0;  // sub=7 -> 5

    float hw0 = h_weight[0], hw1 = h_weight[1], hw2 = h_weight[2], hw3 = h_weight[3];

    float hist[7][DT];
    float lw[7][DT];
    float xfv[7], cnt[7], rate[7];

#pragma unroll
    for (int j = 0; j < 7; j++) {
        cnt[j] = 0.f;
#pragma unroll
        for (int d = 0; d < DT; d++) hist[j][d] = 0.f;
        if (j < cntn) {
            int n = n0 + j;
            xfv[j] = xf[b * NEUR + n];
#pragma unroll
            for (int d = 0; d < DT; d++) lw[j][d] = l_weight[n * DT + d];
        } else {
            xfv[j] = 0.f;
#pragma unroll
            for (int d = 0; d < DT; d++) lw[j][d] = 0.f;
        }
    }

    int wid = tid >> 6;   // 16 waves
    int lane = tid & 63;

    for (int s = 0; s < STEPS; s++) {
        // per-neuron weighted history sums + per-batch partial
        float hsum[7];
        float btl = 0.f;
#pragma unroll
        for (int j = 0; j < 7; j++) {
            hsum[j] = hist[j][0] * lw[j][0] + hist[j][1] * lw[j][1] +
                      hist[j][2] * lw[j][2] + hist[j][3] * lw[j][3];
            btl += hsum[j];
        }
        // segmented reduce across the 8 lanes of this batch
#pragma unroll
        for (int off = 4; off > 0; off >>= 1) btl += __shfl_xor(btl, off, 8);
        // rates + local sum for global mean
        float lsum = 0.f;
#pragma unroll
        for (int j = 0; j < 7; j++) {
            if (j < cntn) {
                float hterm = hist[j][0] * hw0 + hist[j][1] * hw1 +
                              hist[j][2] * hw2 + hist[j][3] * hw3;
                float cur = xfv[j] + (btl - hsum[j]) + hterm;
                rate[j] = expf(cur);
                lsum += rate[j];
            }
        }
        // block-wide sum: wave tree -> 16 partials -> every thread sums 16
#pragma unroll
        for (int off = 32; off > 0; off >>= 1) lsum += __shfl_xor(lsum, off, 64);
        if (lane == 0) red[s & 1][wid] = lsum;
        __syncthreads();
        float tsum = 0.f;
#pragma unroll
        for (int w = 0; w < 16; w++) tsum += red[s & 1][w];
        float thr = tsum * (1.0f / (float)TOT);
        // spike, count, shift history
#pragma unroll
        for (int j = 0; j < 7; j++) {
            if (j < cntn) {
                float sp = (rate[j] > thr) ? 1.0f : 0.0f;
                cnt[j] += sp;
                hist[j][0] = hist[j][1];
                hist[j][1] = hist[j][2];
                hist[j][2] = hist[j][3];
                hist[j][3] = sp;
            }
        }
        // no second barrier: next step writes red[(s+1)&1], a different buffer
    }

#pragma unroll
    for (int j = 0; j < 7; j++) {
        if (j < cntn) {
            float c = cnt[j];
            out[b * NEUR + n0 + j] = c + log1pf(expf(-c));
        }
    }
}

extern "C" void kernel_launch(void* const* d_in, const int* in_sizes, int n_in,
                              void* d_out, int out_size, void* d_ws, size_t ws_size,
                              hipStream_t stream) {
    const float* x = (const float*)d_in[0];
    const float* l_weight = (const float*)d_in[1];
    const float* h_weight = (const float*)d_in[2];
    const float* fc_w = (const float*)d_in[3];
    const float* fc_b = (const float*)d_in[4];
    float* out = (float*)d_out;

    float* xp = (float*)d_ws;                          // [128*5632]  = 2,883,584 B
    float* fc_wt = xp + (size_t)BATCH * K_PAD;         // [5632*64]   = 1,441,792 B
    float* xf = fc_wt + (size_t)K_PAD * 64;            // [6912]      =    27,648 B

    prep_kernel<<<POOL_BLOCKS + TRANS_BLOCKS, 256, 0, stream>>>(x, fc_w, xp, fc_wt);
    fc_kernel<<<BATCH, 512, 0, stream>>>(xp, fc_wt, fc_b, xf);
    recurrence_kernel<<<1, RTPB, 0, stream>>>(xf, l_weight, h_weight, out);
}

// Round 3
// 345.103 us; speedup vs baseline: 1.6913x; 1.1065x over previous
//
#include <hip/hip_runtime.h>
#include <hip/hip_bf16.h>
#include <math.h>

#define BATCH 128
#define NEUR 54
#define DT 4
#define STEPS 30
#define PDIM 75             // pooled spatial dim
#define K (PDIM * PDIM)     // 5625
#define HALF 2816           // half-K, padded to 44*64; h=0 covers [0,2816), h=1 covers [2816,5625)
#define TOT (BATCH * NEUR)  // 6912
#define RTPB 1024

// ---------------- Kernel 1 (fused): pool half-row into LDS, then partial FC --------
// grid = 256 blocks: block = (batch b, half h). 1024 threads.
// Phase 1: avg_pool2d(x,8) for k in [h*HALF, h*HALF+cnt) -> LDS xps[2816] (tail zeroed)
// Phase 2: wave w computes neurons 4w..4w+3: acc over k (k on lanes, coalesced fc_w reads)
//          -> xf_part[h][b][64]
__global__ __launch_bounds__(1024) void poolfc_kernel(const float* __restrict__ x,
                                                      const float* __restrict__ fc_w,
                                                      float* __restrict__ xf_part) {
    __shared__ float xps[HALF];
    int blk = blockIdx.x;
    int b = blk >> 1;
    int h = blk & 1;
    int tid = threadIdx.x;
    int kbase = h * HALF;
    int cnt = h ? (K - HALF) : HALF;  // 2809 or 2816
    const float* xrow = x + (size_t)b * 360000;

    // ---- pool phase ----
    for (int w = tid; w < HALF; w += 1024) {
        float s = 0.f;
        if (w < cnt) {
            int gw = kbase + w;
            int i = gw / PDIM;
            int j = gw - i * PDIM;
            const float* base = xrow + (size_t)(i * 8) * 600 + j * 8;
#pragma unroll
            for (int r = 0; r < 8; r++) {
                const float4* p4 = (const float4*)(base + r * 600);
                float4 a = p4[0];
                float4 c = p4[1];
                s += a.x + a.y + a.z + a.w + c.x + c.y + c.z + c.w;
            }
            s *= (1.0f / 64.0f);
        }
        xps[w] = s;
    }
    __syncthreads();

    // ---- FC phase ----
    int wid = tid >> 6, lane = tid & 63;
    int nb = wid * 4;  // waves 0..13 active (nb<54), waves 14,15 idle
    if (nb < NEUR) {
        int v1 = (nb + 1 < NEUR), v2 = (nb + 2 < NEUR), v3 = (nb + 3 < NEUR);
        int n1 = v1 ? nb + 1 : nb;
        int n2 = v2 ? nb + 2 : nb;
        int n3 = v3 ? nb + 3 : nb;
        const float* p0 = fc_w + (size_t)nb * K + kbase;
        const float* p1 = fc_w + (size_t)n1 * K + kbase;
        const float* p2 = fc_w + (size_t)n2 * K + kbase;
        const float* p3 = fc_w + (size_t)n3 * K + kbase;
        float a0 = 0.f, a1 = 0.f, a2 = 0.f, a3 = 0.f;
        for (int c = 0; c < HALF / 64; c++) {
            int kk = c * 64 + lane;
            float xv = xps[kk];
            bool inb = (kbase + kk) < K;  // guard OOB loads on h=1 tail
            float f0 = inb ? p0[kk] : 0.f;
            float f1 = inb ? p1[kk] : 0.f;
            float f2 = inb ? p2[kk] : 0.f;
            float f3 = inb ? p3[kk] : 0.f;
            a0 += xv * f0;
            a1 += xv * f1;
            a2 += xv * f2;
            a3 += xv * f3;
        }
#pragma unroll
        for (int off = 32; off > 0; off >>= 1) {
            a0 += __shfl_xor(a0, off, 64);
            a1 += __shfl_xor(a1, off, 64);
            a2 += __shfl_xor(a2, off, 64);
            a3 += __shfl_xor(a3, off, 64);
        }
        if (lane == 0) {
            float* dst = xf_part + (size_t)h * (BATCH * 64) + b * 64 + nb;
            dst[0] = a0;
            if (v1) dst[1] = a1;
            if (v2) dst[2] = a2;
            if (v3) dst[3] = a3;
        }
    }
}

// ---------------- Kernel 2: 30-step GLM recurrence, single block --------------------
// 8 threads per batch (8*128 = 1024). Each thread owns <=7 neurons.
// Per-batch lateral total: segmented shfl_xor over 8 lanes.
// Global mean: wave shfl tree -> 16 partials -> double-buffered LDS (float4 reads),
// 1 barrier per step.
__global__ __launch_bounds__(RTPB) void recurrence_kernel(const float* __restrict__ xf_part,
                                                          const float* __restrict__ fc_b,
                                                          const float* __restrict__ l_weight,
                                                          const float* __restrict__ h_weight,
                                                          float* __restrict__ out) {
    __shared__ float red[2][16];

    int tid = threadIdx.x;
    int b = tid >> 3;
    int sub = tid & 7;
    int n0 = sub * 7;
    int cntn = NEUR - n0; if (cntn > 7) cntn = 7; if (cntn < 0) cntn = 0;  // sub=7 -> 5

    float hw0 = h_weight[0], hw1 = h_weight[1], hw2 = h_weight[2], hw3 = h_weight[3];

    float hist[7][DT];
    float lw[7][DT];
    float xfv[7], cnt[7], rate[7];

#pragma unroll
    for (int j = 0; j < 7; j++) {
        cnt[j] = 0.f;
#pragma unroll
        for (int d = 0; d < DT; d++) hist[j][d] = 0.f;
        if (j < cntn) {
            int n = n0 + j;
            xfv[j] = xf_part[b * 64 + n] + xf_part[BATCH * 64 + b * 64 + n] + fc_b[n];
#pragma unroll
            for (int d = 0; d < DT; d++) lw[j][d] = l_weight[n * DT + d];
        } else {
            xfv[j] = 0.f;
#pragma unroll
            for (int d = 0; d < DT; d++) lw[j][d] = 0.f;
        }
    }

    int wid = tid >> 6;  // 16 waves
    int lane = tid & 63;

    for (int s = 0; s < STEPS; s++) {
        float hsum[7];
        float btl = 0.f;
#pragma unroll
        for (int j = 0; j < 7; j++) {
            hsum[j] = hist[j][0] * lw[j][0] + hist[j][1] * lw[j][1] +
                      hist[j][2] * lw[j][2] + hist[j][3] * lw[j][3];
            btl += hsum[j];
        }
#pragma unroll
        for (int off = 4; off > 0; off >>= 1) btl += __shfl_xor(btl, off, 8);
        float lsum = 0.f;
#pragma unroll
        for (int j = 0; j < 7; j++) {
            if (j < cntn) {
                float hterm = hist[j][0] * hw0 + hist[j][1] * hw1 +
                              hist[j][2] * hw2 + hist[j][3] * hw3;
                float cur = xfv[j] + (btl - hsum[j]) + hterm;
                rate[j] = expf(cur);
                lsum += rate[j];
            }
        }
#pragma unroll
        for (int off = 32; off > 0; off >>= 1) lsum += __shfl_xor(lsum, off, 64);
        if (lane == 0) red[s & 1][wid] = lsum;
        __syncthreads();
        const float4* r4 = (const float4*)red[s & 1];
        float4 q0 = r4[0], q1 = r4[1], q2 = r4[2], q3 = r4[3];
        float tsum = ((q0.x + q0.y) + (q0.z + q0.w)) + ((q1.x + q1.y) + (q1.z + q1.w)) +
                     ((q2.x + q2.y) + (q2.z + q2.w)) + ((q3.x + q3.y) + (q3.z + q3.w));
        float thr = tsum * (1.0f / (float)TOT);
#pragma unroll
        for (int j = 0; j < 7; j++) {
            if (j < cntn) {
                float sp = (rate[j] > thr) ? 1.0f : 0.0f;
                cnt[j] += sp;
                hist[j][0] = hist[j][1];
                hist[j][1] = hist[j][2];
                hist[j][2] = hist[j][3];
                hist[j][3] = sp;
            }
        }
        // next step writes red[(s+1)&1] — different buffer, no second barrier needed
    }

#pragma unroll
    for (int j = 0; j < 7; j++) {
        if (j < cntn) {
            float c = cnt[j];
            out[b * NEUR + n0 + j] = c + log1pf(expf(-c));
        }
    }
}

extern "C" void kernel_launch(void* const* d_in, const int* in_sizes, int n_in,
                              void* d_out, int out_size, void* d_ws, size_t ws_size,
                              hipStream_t stream) {
    const float* x = (const float*)d_in[0];
    const float* l_weight = (const float*)d_in[1];
    const float* h_weight = (const float*)d_in[2];
    const float* fc_w = (const float*)d_in[3];
    const float* fc_b = (const float*)d_in[4];
    float* out = (float*)d_out;

    float* xf_part = (float*)d_ws;  // [2][128][64] = 65,536 B

    poolfc_kernel<<<BATCH * 2, 1024, 0, stream>>>(x, fc_w, xf_part);
    recurrence_kernel<<<1, RTPB, 0, stream>>>(xf_part, fc_b, l_weight, h_weight, out);
}

// Round 4
// 343.324 us; speedup vs baseline: 1.7000x; 1.0052x over previous
//
#include <hip/hip_runtime.h>
#include <hip/hip_bf16.h>
#include <math.h>

#define BATCH 128
#define NEUR 54
#define DT 4
#define STEPS 30
#define PDIM 75             // pooled spatial dim
#define K (PDIM * PDIM)     // 5625
#define QK 1408             // quarter-K padded to 22*64; q=3 covers only 1401
#define NQ 4
#define TOT (BATCH * NEUR)  // 6912
#define RTPB 1024

// ---------------- Kernel 1 (fused): pool quarter-row into LDS, then partial FC -----
// grid = 512 blocks: block = (batch b, quarter q). 1024 threads, 2 blocks/CU so the
// HBM-bound pool phase of one block overlaps the L2/VALU-bound FC phase of its
// co-resident neighbor.
__global__ __launch_bounds__(1024) void poolfc_kernel(const float* __restrict__ x,
                                                      const float* __restrict__ fc_w,
                                                      float* __restrict__ xf_part) {
    __shared__ float xps[QK];
    int blk = blockIdx.x;
    int b = blk >> 2;
    int q = blk & 3;
    int tid = threadIdx.x;
    int kbase = q * QK;
    int cnt = (q == 3) ? (K - 3 * QK) : QK;  // 1401 or 1408
    const float* xrow = x + (size_t)b * 360000;

    // ---- pool phase: avg_pool2d(x,8) for this quarter -> LDS (tail zeroed) ----
    for (int w = tid; w < QK; w += 1024) {
        float s = 0.f;
        if (w < cnt) {
            int gw = kbase + w;
            int i = gw / PDIM;
            int j = gw - i * PDIM;
            const float* base = xrow + (size_t)(i * 8) * 600 + j * 8;
#pragma unroll
            for (int r = 0; r < 8; r++) {
                const float4* p4 = (const float4*)(base + r * 600);
                float4 a = p4[0];
                float4 c = p4[1];
                s += a.x + a.y + a.z + a.w + c.x + c.y + c.z + c.w;
            }
            s *= (1.0f / 64.0f);
        }
        xps[w] = s;
    }
    __syncthreads();

    // ---- FC phase: wave w -> neurons 4w..4w+3, k on lanes (coalesced fc_w reads) ----
    int wid = tid >> 6, lane = tid & 63;
    int nb = wid * 4;  // waves 0..13 active, 14/15 idle
    if (nb < NEUR) {
        int v1 = (nb + 1 < NEUR), v2 = (nb + 2 < NEUR), v3 = (nb + 3 < NEUR);
        int n1 = v1 ? nb + 1 : nb;
        int n2 = v2 ? nb + 2 : nb;
        int n3 = v3 ? nb + 3 : nb;
        const float* p0 = fc_w + (size_t)nb * K + kbase;
        const float* p1 = fc_w + (size_t)n1 * K + kbase;
        const float* p2 = fc_w + (size_t)n2 * K + kbase;
        const float* p3 = fc_w + (size_t)n3 * K + kbase;
        float a0 = 0.f, a1 = 0.f, a2 = 0.f, a3 = 0.f;
        int full = (cnt == QK) ? (QK / 64) : (QK / 64 - 1);  // unguarded chunks
        for (int c = 0; c < full; c++) {
            int kk = c * 64 + lane;
            float xv = xps[kk];
            a0 += xv * p0[kk];
            a1 += xv * p1[kk];
            a2 += xv * p2[kk];
            a3 += xv * p3[kk];
        }
        if (cnt != QK) {  // guarded tail chunk (q==3 only)
            int kk = (QK / 64 - 1) * 64 + lane;
            if (kk < cnt) {
                float xv = xps[kk];
                a0 += xv * p0[kk];
                a1 += xv * p1[kk];
                a2 += xv * p2[kk];
                a3 += xv * p3[kk];
            }
        }
#pragma unroll
        for (int off = 32; off > 0; off >>= 1) {
            a0 += __shfl_xor(a0, off, 64);
            a1 += __shfl_xor(a1, off, 64);
            a2 += __shfl_xor(a2, off, 64);
            a3 += __shfl_xor(a3, off, 64);
        }
        if (lane == 0) {
            float* dst = xf_part + (size_t)q * (BATCH * 64) + b * 64 + nb;
            dst[0] = a0;
            if (v1) dst[1] = a1;
            if (v2) dst[2] = a2;
            if (v3) dst[3] = a3;
        }
    }
}

// ---------------- Kernel 2: 30-step GLM recurrence, single block --------------------
// 8 threads per batch (8*128 = 1024), <=7 neurons/thread. Per-batch lateral total via
// segmented shfl_xor(8); global mean via wave tree -> 16 LDS partials (double-
// buffered, 1 barrier/step, float4 readback).
__global__ __launch_bounds__(RTPB) void recurrence_kernel(const float* __restrict__ xf_part,
                                                          const float* __restrict__ fc_b,
                                                          const float* __restrict__ l_weight,
                                                          const float* __restrict__ h_weight,
                                                          float* __restrict__ out) {
    __shared__ float red[2][16];

    int tid = threadIdx.x;
    int b = tid >> 3;
    int sub = tid & 7;
    int n0 = sub * 7;
    int cntn = NEUR - n0; if (cntn > 7) cntn = 7; if (cntn < 0) cntn = 0;  // sub=7 -> 5

    float hw0 = h_weight[0], hw1 = h_weight[1], hw2 = h_weight[2], hw3 = h_weight[3];

    float hist[7][DT];
    float lw[7][DT];
    float xfv[7], cnt[7], rate[7];

#pragma unroll
    for (int j = 0; j < 7; j++) {
        cnt[j] = 0.f;
#pragma unroll
        for (int d = 0; d < DT; d++) hist[j][d] = 0.f;
        if (j < cntn) {
            int n = n0 + j;
            xfv[j] = xf_part[b * 64 + n] + xf_part[BATCH * 64 + b * 64 + n] +
                     xf_part[2 * BATCH * 64 + b * 64 + n] +
                     xf_part[3 * BATCH * 64 + b * 64 + n] + fc_b[n];
#pragma unroll
            for (int d = 0; d < DT; d++) lw[j][d] = l_weight[n * DT + d];
        } else {
            xfv[j] = 0.f;
#pragma unroll
            for (int d = 0; d < DT; d++) lw[j][d] = 0.f;
        }
    }

    int wid = tid >> 6;  // 16 waves
    int lane = tid & 63;

    for (int s = 0; s < STEPS; s++) {
        float hsum[7];
        float btl = 0.f;
#pragma unroll
        for (int j = 0; j < 7; j++) {
            hsum[j] = hist[j][0] * lw[j][0] + hist[j][1] * lw[j][1] +
                      hist[j][2] * lw[j][2] + hist[j][3] * lw[j][3];
            btl += hsum[j];
        }
#pragma unroll
        for (int off = 4; off > 0; off >>= 1) btl += __shfl_xor(btl, off, 8);
        float lsum = 0.f;
#pragma unroll
        for (int j = 0; j < 7; j++) {
            if (j < cntn) {
                float hterm = hist[j][0] * hw0 + hist[j][1] * hw1 +
                              hist[j][2] * hw2 + hist[j][3] * hw3;
                float cur = xfv[j] + (btl - hsum[j]) + hterm;
                rate[j] = expf(cur);
                lsum += rate[j];
            }
        }
#pragma unroll
        for (int off = 32; off > 0; off >>= 1) lsum += __shfl_xor(lsum, off, 64);
        if (lane == 0) red[s & 1][wid] = lsum;
        __syncthreads();
        const float4* r4 = (const float4*)red[s & 1];
        float4 q0 = r4[0], q1 = r4[1], q2 = r4[2], q3 = r4[3];
        float tsum = ((q0.x + q0.y) + (q0.z + q0.w)) + ((q1.x + q1.y) + (q1.z + q1.w)) +
                     ((q2.x + q2.y) + (q2.z + q2.w)) + ((q3.x + q3.y) + (q3.z + q3.w));
        float thr = tsum * (1.0f / (float)TOT);
#pragma unroll
        for (int j = 0; j < 7; j++) {
            if (j < cntn) {
                float sp = (rate[j] > thr) ? 1.0f : 0.0f;
                cnt[j] += sp;
                hist[j][0] = hist[j][1];
                hist[j][1] = hist[j][2];
                hist[j][2] = hist[j][3];
                hist[j][3] = sp;
            }
        }
        // next step writes red[(s+1)&1] — different buffer, no second barrier needed
    }

#pragma unroll
    for (int j = 0; j < 7; j++) {
        if (j < cntn) {
            float c = cnt[j];
            out[b * NEUR + n0 + j] = c + log1pf(expf(-c));
        }
    }
}

extern "C" void kernel_launch(void* const* d_in, const int* in_sizes, int n_in,
                              void* d_out, int out_size, void* d_ws, size_t ws_size,
                              hipStream_t stream) {
    const float* x = (const float*)d_in[0];
    const float* l_weight = (const float*)d_in[1];
    const float* h_weight = (const float*)d_in[2];
    const float* fc_w = (const float*)d_in[3];
    const float* fc_b = (const float*)d_in[4];
    float* out = (float*)d_out;

    float* xf_part = (float*)d_ws;  // [4][128][64] = 131,072 B

    poolfc_kernel<<<BATCH * NQ, 1024, 0, stream>>>(x, fc_w, xf_part);
    recurrence_kernel<<<1, RTPB, 0, stream>>>(xf_part, fc_b, l_weight, h_weight, out);
}